// Round 1
// baseline (85.003 us; speedup 1.0000x reference)
//
#include <hip/hip_runtime.h>
#include <hip/hip_bf16.h>

// Problem: B=32, N=64, D=512, O=256.
// out[b,i,p] = sum_{j != i} relu( u[b,i,p] + v[b,j,p] + c[p] )
//   u = x @ (W2 @ W1[:, :512])^T
//   v = x @ (W2 @ W1[:, 512:])^T
//   c = W2 @ b1 + b2

#define B_ 32
#define N_ 64
#define D_ 512
#define O_ 256
#define R_ (B_ * N_)   // 2048 rows of x

// ---------------------------------------------------------------------------
// Kernel 1: Wf[q][d] = sum_o W2[q&255][o] * W1[o][d + 512*(q>=256)]
//   q in [0,512): rows 0..255 -> U weights (A), rows 256..511 -> V weights (B)
// grid 512 blocks (q), block 512 threads (d)
// ---------------------------------------------------------------------------
__global__ __launch_bounds__(512) void fuse_w_kernel(
    const float* __restrict__ W1, const float* __restrict__ W2,
    float* __restrict__ Wf) {
    int q = blockIdx.x;          // 0..511
    int d = threadIdx.x;         // 0..511
    int p = q & (O_ - 1);
    int off = (q >> 8) * D_;     // 0 or 512
    float acc = 0.f;
#pragma unroll 8
    for (int o = 0; o < O_; ++o)
        acc = fmaf(W2[p * O_ + o], W1[o * (2 * D_) + off + d], acc);
    Wf[q * D_ + d] = acc;
}

// ---------------------------------------------------------------------------
// Kernel 2: c[p] = sum_o W2[p][o]*b1[o] + b2[p]
// ---------------------------------------------------------------------------
__global__ __launch_bounds__(256) void fuse_c_kernel(
    const float* __restrict__ W2, const float* __restrict__ b1,
    const float* __restrict__ b2, float* __restrict__ cvec) {
    int p = threadIdx.x;
    float acc = b2[p];
#pragma unroll 8
    for (int o = 0; o < O_; ++o)
        acc = fmaf(W2[p * O_ + o], b1[o], acc);
    cvec[p] = acc;
}

// ---------------------------------------------------------------------------
// Kernel 3: SGEMM  C[r][q] = sum_d X[r][d] * Wf[q][d]
//   M=2048 (r), N=512 (q), K=512 (d)
//   BM=BN=64, BK=16, 256 threads, 4x4 micro-tile per thread
// ---------------------------------------------------------------------------
__global__ __launch_bounds__(256) void gemm_xw_kernel(
    const float* __restrict__ X, const float* __restrict__ Wf,
    float* __restrict__ C) {
    __shared__ float xs[16][65];
    __shared__ float ws[16][65];
    const int r0 = blockIdx.x * 64;
    const int q0 = blockIdx.y * 64;
    const int tid = threadIdx.x;
    const int ty = tid >> 4;        // 0..15 -> rows ty*4 .. ty*4+3
    const int tx = tid & 15;        // 0..15 -> cols tx*4 .. tx*4+3

    float acc[4][4] = {};

    for (int k0 = 0; k0 < D_; k0 += 16) {
        // load 64x16 tiles of X and Wf (transposed into LDS as [k][row])
#pragma unroll
        for (int t = 0; t < 4; ++t) {
            int e = tid + t * 256;          // 0..1023
            int row = e >> 4;               // 0..63
            int col = e & 15;               // 0..15
            xs[col][row] = X[(r0 + row) * D_ + k0 + col];
            ws[col][row] = Wf[(q0 + row) * D_ + k0 + col];
        }
        __syncthreads();

#pragma unroll
        for (int kk = 0; kk < 16; ++kk) {
            float a[4], w[4];
#pragma unroll
            for (int i = 0; i < 4; ++i) a[i] = xs[kk][ty * 4 + i];
#pragma unroll
            for (int j = 0; j < 4; ++j) w[j] = ws[kk][tx * 4 + j];
#pragma unroll
            for (int i = 0; i < 4; ++i)
#pragma unroll
                for (int j = 0; j < 4; ++j)
                    acc[i][j] = fmaf(a[i], w[j], acc[i][j]);
        }
        __syncthreads();
    }

#pragma unroll
    for (int i = 0; i < 4; ++i)
#pragma unroll
        for (int j = 0; j < 4; ++j)
            C[(r0 + ty * 4 + i) * 512 + q0 + tx * 4 + j] = acc[i][j];
}

// ---------------------------------------------------------------------------
// Kernel 4: pairwise reduction
//   out[b,i,p] = sum_{j != i} relu( U[b,i,p] + V[b,j,p] + c[p] )
//   C layout: C[r][0:256] = U, C[r][256:512] = V, r = b*64 + n
// grid 2048 blocks (b*64+i), block 256 threads (p)
// ---------------------------------------------------------------------------
__global__ __launch_bounds__(256) void pairwise_kernel(
    const float* __restrict__ C, const float* __restrict__ cvec,
    float* __restrict__ out) {
    const int bi = blockIdx.x;      // 0..2047
    const int b = bi >> 6;
    const int i = bi & 63;
    const int p = threadIdx.x;

    const float u = C[bi * 512 + p] + cvec[p];
    const float* Vb = C + (b * 64) * 512 + 256 + p;

    float acc = 0.f;
#pragma unroll 16
    for (int j = 0; j < 64; ++j) {
        float s = u + Vb[j * 512];
        acc += fmaxf(s, 0.f);
    }
    // remove the diagonal term j == i
    acc -= fmaxf(u + Vb[i * 512], 0.f);

    out[bi * 256 + p] = acc;
}

// ---------------------------------------------------------------------------
extern "C" void kernel_launch(void* const* d_in, const int* in_sizes, int n_in,
                              void* d_out, int out_size, void* d_ws, size_t ws_size,
                              hipStream_t stream) {
    const float* x  = (const float*)d_in[0];   // (32,64,512)
    const float* W1 = (const float*)d_in[1];   // (256,1024)
    const float* b1 = (const float*)d_in[2];   // (256,)
    const float* W2 = (const float*)d_in[3];   // (256,256)
    const float* b2 = (const float*)d_in[4];   // (256,)
    float* out = (float*)d_out;                // (32,64,256)

    // workspace layout (floats):
    //   Wf:   512*512            @ 0
    //   cvec: 256                @ 262144
    //   C:    2048*512           @ 262400
    float* Wf   = (float*)d_ws;
    float* cvec = Wf + 512 * 512;
    float* Cbuf = cvec + 256;

    fuse_w_kernel<<<512, 512, 0, stream>>>(W1, W2, Wf);
    fuse_c_kernel<<<1, 256, 0, stream>>>(W2, b1, b2, cvec);
    gemm_xw_kernel<<<dim3(R_ / 64, 512 / 64), 256, 0, stream>>>(x, Wf, Cbuf);
    pairwise_kernel<<<R_, 256, 0, stream>>>(Cbuf, cvec, out);
}

// Round 2
// 29.274 us; speedup vs baseline: 2.9037x; 2.9037x over previous
//
#include <hip/hip_runtime.h>
#include <hip/hip_bf16.h>

// out[b,i,p] = sum_{j!=i} relu( u[b,i,p] + v[b,j,p] + c[p] )
//   H  = x @ W1r^T          (2048x512, bf16 MFMA)   W1r[q'][d] = W1[q'&255][(q'>>8)*512+d]
//   u  = H[:, 0:256] @ W2^T ; v = H[:,256:512] @ W2^T   (fused with pairwise reduce)
//   c  = W2 @ b1 + b2

typedef unsigned short u16;
typedef __attribute__((ext_vector_type(8))) short short8v;
typedef __attribute__((ext_vector_type(4))) float float4v;

typedef __attribute__((address_space(1))) const unsigned char* gas_ptr;
typedef __attribute__((address_space(3))) unsigned char* las_ptr;

__device__ __forceinline__ void lds_load16(const void* g, void* l) {
    __builtin_amdgcn_global_load_lds((gas_ptr)g, (las_ptr)l, 16, 0, 0);
}

__device__ __forceinline__ u16 f2bf(float f) {
    unsigned u = __float_as_uint(f);
    return (u16)((u + 0x7fffu + ((u >> 16) & 1u)) >> 16);
}

__device__ __forceinline__ void cvt8(const float* __restrict__ s, u16* __restrict__ d) {
    float4v a = *(const float4v*)s;
    float4v b = *(const float4v*)(s + 4);
    union { u16 us[8]; short8v v; } o;
    o.us[0] = f2bf(a.x); o.us[1] = f2bf(a.y); o.us[2] = f2bf(a.z); o.us[3] = f2bf(a.w);
    o.us[4] = f2bf(b.x); o.us[5] = f2bf(b.y); o.us[6] = f2bf(b.z); o.us[7] = f2bf(b.w);
    *(short8v*)d = o.v;
}

// ---------------------------------------------------------------------------
// prep: bf16 conversions + cvec
//   blocks   0..511 : x  (2048x512) -> xb
//   blocks 512..639 : W1 -> W1r (rearranged [512][512])
//   blocks 640..671 : W2 -> W2b
//   block  672      : cvec[p] = sum_o W2[p][o]*b1[o] + b2[p]  (fp32)
// ---------------------------------------------------------------------------
__global__ __launch_bounds__(256) void prep_kernel(
    const float* __restrict__ x, const float* __restrict__ W1,
    const float* __restrict__ b1, const float* __restrict__ W2,
    const float* __restrict__ b2,
    u16* __restrict__ xb, u16* __restrict__ W1r, u16* __restrict__ W2b,
    float* __restrict__ cvec) {
    int bid = blockIdx.x, t = threadIdx.x;
    if (bid < 512) {
        int e = bid * 2048 + t * 8;
        cvt8(x + e, xb + e);
    } else if (bid < 640) {
        int e = (bid - 512) * 2048 + t * 8;     // 0..262143
        int q = e >> 9, d = e & 511;
        cvt8(W1 + (q & 255) * 1024 + (q >> 8) * 512 + d, W1r + e);
    } else if (bid < 672) {
        int e = (bid - 640) * 2048 + t * 8;     // 0..65535
        cvt8(W2 + e, W2b + e);
    } else {
        float acc = b2[t];
        const float4v* wrow = (const float4v*)(W2 + t * 256);
#pragma unroll 8
        for (int o4 = 0; o4 < 64; ++o4) {
            float4v wv = wrow[o4];
            float4v bv = *(const float4v*)(b1 + o4 * 4);
            acc += wv.x * bv.x + wv.y * bv.y + wv.z * bv.z + wv.w * bv.w;
        }
        cvec[t] = acc;
    }
}

// ---------------------------------------------------------------------------
// hgemm: Hb[r][q'] = sum_d xb[r][d] * W1r[q'][d]   (bf16 in, bf16 out)
//   M=2048, N=512, K=512. 64x64 tiles -> grid(32,8)=256 blocks, 4 waves.
//   Whole-K panels in LDS (64KB+64KB), XOR-swizzled via pre-swizzled source.
// ---------------------------------------------------------------------------
__global__ __launch_bounds__(256) void hgemm_kernel(
    const u16* __restrict__ xb, const u16* __restrict__ W1r,
    u16* __restrict__ Hb) {
    __shared__ __align__(16) u16 As[64 * 512];
    __shared__ __align__(16) u16 Bs[64 * 512];
    const int r0 = blockIdx.x * 64;
    const int q0 = blockIdx.y * 64;
    const int tid = threadIdx.x;
    const int lane = tid & 63, w = tid >> 6;

    // stage: one global_load_lds per 64-row; lane fetches chunk (lane ^ (row&7))
#pragma unroll 4
    for (int rr = 0; rr < 16; ++rr) {
        int row = w * 16 + rr;
        int sc = lane ^ (row & 7);
        lds_load16(xb + (r0 + row) * 512 + sc * 8, (void*)&As[row * 512]);
        lds_load16(W1r + (q0 + row) * 512 + sc * 8, (void*)&Bs[row * 512]);
    }
    __syncthreads();

    const int wm = w >> 1, wn = w & 1;
    const int rQ = lane >> 4, rM = lane & 15;
    float4v acc[2][2] = {};
    for (int ks = 0; ks < 16; ++ks) {
        short8v a[2], bf[2];
#pragma unroll
        for (int mf = 0; mf < 2; ++mf) {
            int row = wm * 32 + mf * 16 + rM;
            int unit = row * 64 + ((ks * 4 + rQ) ^ (row & 7));
            a[mf] = *(const short8v*)((const char*)As + unit * 16);
        }
#pragma unroll
        for (int nf = 0; nf < 2; ++nf) {
            int row = wn * 32 + nf * 16 + rM;
            int unit = row * 64 + ((ks * 4 + rQ) ^ (row & 7));
            bf[nf] = *(const short8v*)((const char*)Bs + unit * 16);
        }
#pragma unroll
        for (int mf = 0; mf < 2; ++mf)
#pragma unroll
            for (int nf = 0; nf < 2; ++nf)
                acc[mf][nf] = __builtin_amdgcn_mfma_f32_16x16x32_bf16(
                    a[mf], bf[nf], acc[mf][nf], 0, 0, 0);
    }

#pragma unroll
    for (int mf = 0; mf < 2; ++mf)
#pragma unroll
        for (int nf = 0; nf < 2; ++nf)
#pragma unroll
            for (int r = 0; r < 4; ++r) {
                int orow = r0 + wm * 32 + mf * 16 + rQ * 4 + r;
                int ocol = q0 + wn * 32 + nf * 16 + rM;
                Hb[orow * 512 + ocol] = f2bf(acc[mf][nf][r]);
            }
}

// ---------------------------------------------------------------------------
// uvpair: per block (b, pc): u/v[64][32] via MFMA (K=256), then
//   out[b,i,p0+p] = sum_{j!=i} relu(u[i][p]+v[j][p]+cvec[p0+p])
//   grid 256 blocks (b = bid>>3, pc = bid&7), 4 waves:
//   wave w: uv=w&1 (0->u,1->v), rh=w>>1 (row half)
// ---------------------------------------------------------------------------
__global__ __launch_bounds__(256) void uvpair_kernel(
    const u16* __restrict__ Hb, const u16* __restrict__ W2b,
    const float* __restrict__ cvec, float* __restrict__ out) {
    __shared__ __align__(16) unsigned char smem[81920];
    u16* Hs = (u16*)smem;                 // 64 x 512 bf16 (64 KB)
    u16* Ws = (u16*)(smem + 65536);       // 32 x 256 bf16 (16 KB)
    const int bid = blockIdx.x;
    const int b = bid >> 3, pc = bid & 7;
    const int p0 = pc * 32;
    const int tid = threadIdx.x;
    const int lane = tid & 63, w = tid >> 6;

#pragma unroll 4
    for (int rr = 0; rr < 16; ++rr) {
        int row = w * 16 + rr;
        int sc = lane ^ (row & 7);
        lds_load16(Hb + (b * 64 + row) * 512 + sc * 8, (void*)&Hs[row * 512]);
    }
#pragma unroll
    for (int q = 0; q < 4; ++q) {
        int rbase = w * 8 + q * 2;
        int prow = rbase + (lane >> 5);
        int u = lane & 31;
        int sc = u ^ (prow & 7);
        lds_load16(W2b + (p0 + prow) * 256 + sc * 8, (void*)&Ws[rbase * 256]);
    }
    __syncthreads();

    const int uv = w & 1, rh = w >> 1;
    const int rQ = lane >> 4, rM = lane & 15;
    float4v acc[2][2] = {};
    for (int ks = 0; ks < 8; ++ks) {
        short8v a[2], bf[2];
#pragma unroll
        for (int mf = 0; mf < 2; ++mf) {
            int row = rh * 32 + mf * 16 + rM;
            int kc = uv * 32 + ks * 4 + rQ;
            int unit = row * 64 + (kc ^ (row & 7));
            a[mf] = *(const short8v*)((const char*)Hs + unit * 16);
        }
#pragma unroll
        for (int nf = 0; nf < 2; ++nf) {
            int row = nf * 16 + rM;
            int unit = row * 32 + ((ks * 4 + rQ) ^ (row & 7));
            bf[nf] = *(const short8v*)((const char*)Ws + unit * 16);
        }
#pragma unroll
        for (int mf = 0; mf < 2; ++mf)
#pragma unroll
            for (int nf = 0; nf < 2; ++nf)
                acc[mf][nf] = __builtin_amdgcn_mfma_f32_16x16x32_bf16(
                    a[mf], bf[nf], acc[mf][nf], 0, 0, 0);
    }

    __syncthreads();   // done reading Hs/Ws; reuse LDS for U/V (fp32, stride 33)
    float* Us = (float*)smem;             // 64 x 33
    float* Vs = (float*)smem + 64 * 33;   // 64 x 33
    float* dst = uv ? Vs : Us;
#pragma unroll
    for (int mf = 0; mf < 2; ++mf)
#pragma unroll
        for (int nf = 0; nf < 2; ++nf)
#pragma unroll
            for (int r = 0; r < 4; ++r)
                dst[(rh * 32 + mf * 16 + rQ * 4 + r) * 33 + nf * 16 + rM] =
                    acc[mf][nf][r];
    __syncthreads();

    // pairwise reduce: thread -> p = tid&31, rows g*8..g*8+7 (g = tid>>5)
    const int p = tid & 31;
    const int g = tid >> 5;
    const float cv = cvec[p0 + p];
    float ufull[8], red[8];
#pragma unroll
    for (int ii = 0; ii < 8; ++ii) {
        ufull[ii] = Us[(g * 8 + ii) * 33 + p] + cv;
        red[ii] = 0.f;
    }
#pragma unroll 4
    for (int j = 0; j < 64; ++j) {
        float vs = Vs[j * 33 + p];
#pragma unroll
        for (int ii = 0; ii < 8; ++ii)
            red[ii] += fmaxf(ufull[ii] + vs, 0.f);
    }
#pragma unroll
    for (int ii = 0; ii < 8; ++ii) {
        int i = g * 8 + ii;
        red[ii] -= fmaxf(ufull[ii] + Vs[i * 33 + p], 0.f);
        out[(b * 64 + i) * 256 + p0 + p] = red[ii];
    }
}

// ---------------------------------------------------------------------------
extern "C" void kernel_launch(void* const* d_in, const int* in_sizes, int n_in,
                              void* d_out, int out_size, void* d_ws, size_t ws_size,
                              hipStream_t stream) {
    const float* x  = (const float*)d_in[0];   // (32,64,512)
    const float* W1 = (const float*)d_in[1];   // (256,1024)
    const float* b1 = (const float*)d_in[2];   // (256,)
    const float* W2 = (const float*)d_in[3];   // (256,256)
    const float* b2 = (const float*)d_in[4];   // (256,)
    float* out = (float*)d_out;                // (32,64,256)

    // workspace: xb(2MB) | W1r(512KB) | W2b(128KB) | cvec(1KB) | Hb(2MB)
    u16* xb   = (u16*)d_ws;                    // 2048*512
    u16* W1r  = xb + 2048 * 512;               // 512*512
    u16* W2b  = W1r + 512 * 512;               // 256*256
    float* cvec = (float*)(W2b + 256 * 256);   // 256
    u16* Hb   = (u16*)(cvec + 256);            // 2048*512

    prep_kernel<<<673, 256, 0, stream>>>(x, W1, b1, W2, b2, xb, W1r, W2b, cvec);
    hgemm_kernel<<<dim3(32, 8), 256, 0, stream>>>(xb, W1r, Hb);
    uvpair_kernel<<<256, 256, 0, stream>>>(Hb, W2b, cvec, out);
}

// Round 3
// 25.051 us; speedup vs baseline: 3.3932x; 1.1686x over previous
//
#include <hip/hip_runtime.h>
#include <hip/hip_bf16.h>

// out[b,i,p] = sum_{j!=i} relu( u[b,i,p] + v[b,j,p] + c[p] )
//   H  = x @ W1r^T  (2048x512 bf16, MFMA; W1r[q'][d] = W1[q'&255][(q'>>8)*512+d])
//   u  = H[:,0:256] @ W2^T ; v = H[:,256:512] @ W2^T (fused with pairwise reduce)
//   c  = W2 @ b1 + b2

typedef unsigned short u16;
typedef __attribute__((ext_vector_type(8))) short short8v;
typedef __attribute__((ext_vector_type(4))) float float4v;

typedef __attribute__((address_space(1))) const unsigned char* gas_ptr;
typedef __attribute__((address_space(3))) unsigned char* las_ptr;

__device__ __forceinline__ void lds_load16(const void* g, void* l) {
    __builtin_amdgcn_global_load_lds((gas_ptr)g, (las_ptr)l, 16, 0, 0);
}

__device__ __forceinline__ u16 f2bf(float f) {
    unsigned u = __float_as_uint(f);
    return (u16)((u + 0x7fffu + ((u >> 16) & 1u)) >> 16);
}

__device__ __forceinline__ short8v cvt8v(float4v a, float4v b) {
    union { u16 us[8]; short8v v; } o;
    o.us[0] = f2bf(a.x); o.us[1] = f2bf(a.y); o.us[2] = f2bf(a.z); o.us[3] = f2bf(a.w);
    o.us[4] = f2bf(b.x); o.us[5] = f2bf(b.y); o.us[6] = f2bf(b.z); o.us[7] = f2bf(b.w);
    return o.v;
}

// ---------------------------------------------------------------------------
// stage1: Hb[r][q'] = bf16( sum_d x[r][d] * W1r[q'][d] )
//   grid 257 blocks x 512 threads. blocks 0..255: GEMM tile (r=bid&31, q=bid>>5)
//   block 256: cvec[p] = sum_o W2[p][o]*b1[o] + b2[p]
//   Staging: global fp32 -> reg -> cvt bf16 -> XOR-swizzled ds_write_b128.
// ---------------------------------------------------------------------------
__global__ __launch_bounds__(512) void stage1_kernel(
    const float* __restrict__ x, const float* __restrict__ W1,
    const float* __restrict__ b1, const float* __restrict__ W2,
    const float* __restrict__ b2,
    u16* __restrict__ Hb, float* __restrict__ cvec) {
    const int bid = blockIdx.x;
    const int tid = threadIdx.x;
    if (bid == 256) {
        if (tid < 256) {
            float acc = b2[tid];
            const float4v* wrow = (const float4v*)(W2 + tid * 256);
#pragma unroll 8
            for (int o4 = 0; o4 < 64; ++o4) {
                float4v wv = wrow[o4];
                float4v bv = *(const float4v*)(b1 + o4 * 4);
                acc += wv.x * bv.x + wv.y * bv.y + wv.z * bv.z + wv.w * bv.w;
            }
            cvec[tid] = acc;
        }
        return;
    }

    __shared__ __align__(16) u16 As[64 * 512];
    __shared__ __align__(16) u16 Bs[64 * 512];
    const int r0 = (bid & 31) * 64;     // same-r blocks share XCD (bid mod 8 const)
    const int q0 = (bid >> 5) * 64;
    const int lane = tid & 63, w = tid >> 6;   // 8 waves

    // reg-stage + convert: each wave does 8 rows of As and Bs
#pragma unroll 4
    for (int rr = 0; rr < 8; ++rr) {
        int row = w * 8 + rr;
        const float* sA = x + (r0 + row) * 512 + lane * 8;
        int qrow = q0 + row;
        const float* sB = W1 + (qrow & 255) * 1024 + (qrow >> 8) * 512 + lane * 8;
        float4v a0 = *(const float4v*)sA;
        float4v a1 = *(const float4v*)(sA + 4);
        float4v c0 = *(const float4v*)sB;
        float4v c1 = *(const float4v*)(sB + 4);
        int du = (lane ^ (row & 7)) * 8;
        *(short8v*)&As[row * 512 + du] = cvt8v(a0, a1);
        *(short8v*)&Bs[row * 512 + du] = cvt8v(c0, c1);
    }
    __syncthreads();

    // 8 waves: wave tile 32 rows x 16 cols  (wm=w>>2, wn=w&3)
    const int wm = w >> 2, wn = w & 3;
    const int rQ = lane >> 4, rM = lane & 15;
    float4v acc[2] = {};
    for (int ks = 0; ks < 16; ++ks) {
        short8v a[2], bv;
#pragma unroll
        for (int mf = 0; mf < 2; ++mf) {
            int row = wm * 32 + mf * 16 + rM;
            int unit = row * 64 + ((ks * 4 + rQ) ^ (row & 7));
            a[mf] = *(const short8v*)((const char*)As + unit * 16);
        }
        {
            int row = wn * 16 + rM;
            int unit = row * 64 + ((ks * 4 + rQ) ^ (row & 7));
            bv = *(const short8v*)((const char*)Bs + unit * 16);
        }
#pragma unroll
        for (int mf = 0; mf < 2; ++mf)
            acc[mf] = __builtin_amdgcn_mfma_f32_16x16x32_bf16(a[mf], bv, acc[mf], 0, 0, 0);
    }

#pragma unroll
    for (int mf = 0; mf < 2; ++mf)
#pragma unroll
        for (int r = 0; r < 4; ++r) {
            int orow = r0 + wm * 32 + mf * 16 + rQ * 4 + r;
            int ocol = q0 + wn * 16 + rM;
            Hb[orow * 512 + ocol] = f2bf(acc[mf][r]);
        }
}

// ---------------------------------------------------------------------------
// uvpair: per block (b=bid&31, pc=bid>>5): u/v[64][32] via MFMA (K=256), then
//   out[b,i,p0+p] = sum_{j!=i} relu(u[i][p]+v[j][p]+cvec[p0+p])
//   4 waves: wave w -> uv=w&1 (0->u,1->v), rh=w>>1 (row half)
// ---------------------------------------------------------------------------
__global__ __launch_bounds__(256) void uvpair_kernel(
    const u16* __restrict__ Hb, const float* __restrict__ W2,
    const float* __restrict__ cvec, float* __restrict__ out) {
    __shared__ __align__(16) unsigned char smem[81920];
    u16* Hs = (u16*)smem;                 // 64 x 512 bf16 (64 KB)
    u16* Ws = (u16*)(smem + 65536);       // 32 x 256 bf16 (16 KB)
    const int bid = blockIdx.x;
    const int b = bid & 31, pc = bid >> 5;   // same-b blocks share XCD
    const int p0 = pc * 32;
    const int tid = threadIdx.x;
    const int lane = tid & 63, w = tid >> 6;

    // Hs: fire-and-forget direct-to-LDS (bf16 already), pre-swizzled source
#pragma unroll 4
    for (int rr = 0; rr < 16; ++rr) {
        int row = w * 16 + rr;
        int sc = lane ^ (row & 7);
        lds_load16(Hb + (b * 64 + row) * 512 + sc * 8, (void*)&Hs[row * 512]);
    }
    // Ws: reg-stage W2 fp32 -> bf16 (hides under the Hs loads)
#pragma unroll
    for (int rr = 0; rr < 4; ++rr) {
        int row = w * 8 + rr * 2 + (lane >> 5);   // 0..31
        int u = lane & 31;
        const float* s = W2 + (p0 + row) * 256 + u * 8;
        float4v c0 = *(const float4v*)s;
        float4v c1 = *(const float4v*)(s + 4);
        int du = (u ^ (row & 7)) * 8;
        *(short8v*)&Ws[row * 256 + du] = cvt8v(c0, c1);
    }
    __syncthreads();

    const int uv = w & 1, rh = w >> 1;
    const int rQ = lane >> 4, rM = lane & 15;
    float4v acc[2][2] = {};
    for (int ks = 0; ks < 8; ++ks) {
        short8v a[2], bf[2];
#pragma unroll
        for (int mf = 0; mf < 2; ++mf) {
            int row = rh * 32 + mf * 16 + rM;
            int kc = uv * 32 + ks * 4 + rQ;
            int unit = row * 64 + (kc ^ (row & 7));
            a[mf] = *(const short8v*)((const char*)Hs + unit * 16);
        }
#pragma unroll
        for (int nf = 0; nf < 2; ++nf) {
            int row = nf * 16 + rM;
            int unit = row * 32 + ((ks * 4 + rQ) ^ (row & 7));
            bf[nf] = *(const short8v*)((const char*)Ws + unit * 16);
        }
#pragma unroll
        for (int mf = 0; mf < 2; ++mf)
#pragma unroll
            for (int nf = 0; nf < 2; ++nf)
                acc[mf][nf] = __builtin_amdgcn_mfma_f32_16x16x32_bf16(
                    a[mf], bf[nf], acc[mf][nf], 0, 0, 0);
    }

    __syncthreads();   // reuse LDS for U/V (fp32, stride 33: conflict-free)
    float* Us = (float*)smem;             // 64 x 33
    float* Vs = (float*)smem + 64 * 33;   // 64 x 33
    float* dst = uv ? Vs : Us;
#pragma unroll
    for (int mf = 0; mf < 2; ++mf)
#pragma unroll
        for (int nf = 0; nf < 2; ++nf)
#pragma unroll
            for (int r = 0; r < 4; ++r)
                dst[(rh * 32 + mf * 16 + rQ * 4 + r) * 33 + nf * 16 + rM] =
                    acc[mf][nf][r];
    __syncthreads();

    // pairwise reduce: thread -> p = tid&31, rows g*8..g*8+7 (g = tid>>5)
    const int p = tid & 31;
    const int g = tid >> 5;
    const float cv = cvec[p0 + p];
    float ufull[8], red[8];
#pragma unroll
    for (int ii = 0; ii < 8; ++ii) {
        ufull[ii] = Us[(g * 8 + ii) * 33 + p] + cv;
        red[ii] = 0.f;
    }
#pragma unroll 4
    for (int j = 0; j < 64; ++j) {
        float vs = Vs[j * 33 + p];
#pragma unroll
        for (int ii = 0; ii < 8; ++ii)
            red[ii] += fmaxf(ufull[ii] + vs, 0.f);
    }
#pragma unroll
    for (int ii = 0; ii < 8; ++ii) {
        int i = g * 8 + ii;
        red[ii] -= fmaxf(ufull[ii] + Vs[i * 33 + p], 0.f);
        out[(b * 64 + i) * 256 + p0 + p] = red[ii];
    }
}

// ---------------------------------------------------------------------------
extern "C" void kernel_launch(void* const* d_in, const int* in_sizes, int n_in,
                              void* d_out, int out_size, void* d_ws, size_t ws_size,
                              hipStream_t stream) {
    const float* x  = (const float*)d_in[0];   // (32,64,512)
    const float* W1 = (const float*)d_in[1];   // (256,1024)
    const float* b1 = (const float*)d_in[2];   // (256,)
    const float* W2 = (const float*)d_in[3];   // (256,256)
    const float* b2 = (const float*)d_in[4];   // (256,)
    float* out = (float*)d_out;                // (32,64,256)

    // workspace: Hb (2048*512 bf16 = 2MB) | cvec (256 f32)
    u16* Hb = (u16*)d_ws;
    float* cvec = (float*)(Hb + 2048 * 512);

    stage1_kernel<<<257, 512, 0, stream>>>(x, W1, b1, W2, b2, Hb, cvec);
    uvpair_kernel<<<256, 256, 0, stream>>>(Hb, W2, cvec, out);
}

// Round 4
// 21.365 us; speedup vs baseline: 3.9787x; 1.1725x over previous
//
#include <hip/hip_runtime.h>
#include <hip/hip_bf16.h>

// out[b,i,p] = sum_{j!=i} relu( U[b,i,p] + V[b,j,p] + c[p] )
//   Wf[q][d] = sum_o W2[q&255][o] * W1[o][(q>=256)*512 + d]   (512x512, bf16)
//   [U|V][r][q] = sum_d x[r][d] * Wf[q][d]                    (one K=512 MFMA GEMM)
//   c[p] = sum_o W2[p][o]*b1[o] + b2[p]

typedef unsigned short u16;
typedef __attribute__((ext_vector_type(8))) short short8v;
typedef __attribute__((ext_vector_type(4))) short short4v;
typedef __attribute__((ext_vector_type(4))) float float4v;

typedef __attribute__((address_space(1))) const unsigned char* gas_ptr;
typedef __attribute__((address_space(3))) unsigned char* las_ptr;

__device__ __forceinline__ void lds_load16(const void* g, void* l) {
    __builtin_amdgcn_global_load_lds((gas_ptr)g, (las_ptr)l, 16, 0, 0);
}

__device__ __forceinline__ u16 f2bf(float f) {
    unsigned u = __float_as_uint(f);
    return (u16)((u + 0x7fffu + ((u >> 16) & 1u)) >> 16);
}

__device__ __forceinline__ short8v cvt8v(float4v a, float4v b) {
    union { u16 us[8]; short8v v; } o;
    o.us[0] = f2bf(a.x); o.us[1] = f2bf(a.y); o.us[2] = f2bf(a.z); o.us[3] = f2bf(a.w);
    o.us[4] = f2bf(b.x); o.us[5] = f2bf(b.y); o.us[6] = f2bf(b.z); o.us[7] = f2bf(b.w);
    return o.v;
}

// ---------------------------------------------------------------------------
// prep: blocks 0..63 -> Wfb tiles (64q x 64d, K=256 MFMA); block 64 -> cvec.
//   As[64][264 u16]: W2 rows (padded 33 units/row).
//   Bt[64][264 u16]: W1 tile transposed (Bt[d][o]); unit-XOR by (d>>3)&7.
// ---------------------------------------------------------------------------
__global__ __launch_bounds__(256) void prep_kernel(
    const float* __restrict__ W1, const float* __restrict__ b1,
    const float* __restrict__ W2, const float* __restrict__ b2,
    u16* __restrict__ Wfb, float* __restrict__ cvec) {
    const int bid = blockIdx.x;
    const int t = threadIdx.x;
    if (bid == 64) {
        float acc = b2[t];
        const float4v* wrow = (const float4v*)(W2 + t * 256);
#pragma unroll 8
        for (int o4 = 0; o4 < 64; ++o4) {
            float4v wv = wrow[o4];
            float4v bv = *(const float4v*)(b1 + o4 * 4);
            acc += wv.x * bv.x + wv.y * bv.y + wv.z * bv.z + wv.w * bv.w;
        }
        cvec[t] = acc;
        return;
    }

    __shared__ __align__(16) u16 As[64 * 264];
    __shared__ __align__(16) u16 Bt[64 * 264];
    const int qt = bid >> 3, dt = bid & 7;
    const int q0 = qt * 64, d0 = dt * 64;
    const int p0 = q0 & 255;
    const int off = (q0 & 256) * 2;          // 0 or 512
    const int lane = t & 63, w = t >> 6;     // 4 waves

    // stage As = W2[p0..p0+63][0..255] -> bf16, row stride 33 units
#pragma unroll
    for (int rr = 0; rr < 8; ++rr) {
        int row = w * 16 + rr * 2 + (lane >> 5);
        int c = lane & 31;
        const float* s = W2 + (p0 + row) * 256 + c * 8;
        float4v a0 = *(const float4v*)s, a1 = *(const float4v*)(s + 4);
        *(short8v*)&As[row * 264 + c * 8] = cvt8v(a0, a1);
    }
    // stage Bt[d][o] = W1[o][off+d0+d] via in-register 4x4 transpose + b64 writes
#pragma unroll
    for (int kk = 0; kk < 4; ++kk) {
        const int m = t & 15, og = t >> 4;
        const int o0 = kk * 64 + og * 4;
        const int d4 = m * 4;
        float4v f0 = *(const float4v*)(W1 + (o0 + 0) * 1024 + off + d0 + d4);
        float4v f1 = *(const float4v*)(W1 + (o0 + 1) * 1024 + off + d0 + d4);
        float4v f2 = *(const float4v*)(W1 + (o0 + 2) * 1024 + off + d0 + d4);
        float4v f3 = *(const float4v*)(W1 + (o0 + 3) * 1024 + off + d0 + d4);
        const int u = o0 >> 3, sub = o0 & 7;
#pragma unroll
        for (int dd = 0; dd < 4; ++dd) {
            int d = d4 + dd;
            int usw = u ^ ((d >> 3) & 7);
            union { u16 us[4]; short4v v; } pk;
            pk.us[0] = f2bf(f0[dd]); pk.us[1] = f2bf(f1[dd]);
            pk.us[2] = f2bf(f2[dd]); pk.us[3] = f2bf(f3[dd]);
            *(short4v*)&Bt[d * 264 + usw * 8 + sub] = pk.v;
        }
    }
    __syncthreads();

    const int wm = w >> 1, wn = w & 1;
    const int rQ = lane >> 4, rM = lane & 15;
    float4v acc[2][2] = {};
#pragma unroll
    for (int ks = 0; ks < 8; ++ks) {
        short8v a[2], bf[2];
#pragma unroll
        for (int mf = 0; mf < 2; ++mf) {
            int row = wm * 32 + mf * 16 + rM;
            a[mf] = *(const short8v*)&As[row * 264 + (ks * 4 + rQ) * 8];
        }
#pragma unroll
        for (int nf = 0; nf < 2; ++nf) {
            int drow = wn * 32 + nf * 16 + rM;
            int ku = (ks * 4 + rQ) ^ ((drow >> 3) & 7);
            bf[nf] = *(const short8v*)&Bt[drow * 264 + ku * 8];
        }
#pragma unroll
        for (int mf = 0; mf < 2; ++mf)
#pragma unroll
            for (int nf = 0; nf < 2; ++nf)
                acc[mf][nf] = __builtin_amdgcn_mfma_f32_16x16x32_bf16(
                    a[mf], bf[nf], acc[mf][nf], 0, 0, 0);
    }

#pragma unroll
    for (int mf = 0; mf < 2; ++mf)
#pragma unroll
        for (int nf = 0; nf < 2; ++nf)
#pragma unroll
            for (int r = 0; r < 4; ++r) {
                int q = q0 + wm * 32 + mf * 16 + rQ * 4 + r;
                int d = d0 + wn * 32 + nf * 16 + rM;
                Wfb[q * 512 + d] = f2bf(acc[mf][nf][r]);
            }
}

// ---------------------------------------------------------------------------
// fused: block (b = bid&31, pc = bid>>5), 512 threads (8 waves).
//   Xs[64][520 u16], Ws[64][520 u16] (65-unit padded rows).
//   Ws rows 0..31 = Wf U-rows (q = pc*32+row), 32..63 = V-rows (q = 256+pc*32+row-32).
//   Wave w: uv = w&1, rh = w>>1 -> 16 x-rows, 32 p-cols. K=512 (16 ks).
//   Epilogue: U/V -> LDS [64][33] f32, pairwise reduce, write out.
// ---------------------------------------------------------------------------
__global__ __launch_bounds__(512) void fused_kernel(
    const float* __restrict__ x, const u16* __restrict__ Wfb,
    const float* __restrict__ cvec, float* __restrict__ out) {
    __shared__ __align__(16) u16 smem[2 * 64 * 520];   // 133120 B
    u16* Xs = smem;
    u16* Ws = smem + 64 * 520;
    const int bid = blockIdx.x;
    const int b = bid & 31, pc = bid >> 5;   // same-b blocks share XCD
    const int p0 = pc * 32;
    const int tid = threadIdx.x;
    const int lane = tid & 63, w = tid >> 6;

    // Ws: direct global->LDS (bf16 already), linear rows with inter-row padding
#pragma unroll
    for (int rr = 0; rr < 8; ++rr) {
        int row = w * 8 + rr;
        int q = (row < 32) ? (p0 + row) : (256 + p0 + (row - 32));
        lds_load16(Wfb + q * 512 + lane * 8, (void*)&Ws[row * 520]);
    }
    // Xs: fp32 -> bf16 reg-stage
#pragma unroll
    for (int rr = 0; rr < 8; ++rr) {
        int row = w * 8 + rr;
        const float* s = x + (b * 64 + row) * 512 + lane * 8;
        float4v a0 = *(const float4v*)s, a1 = *(const float4v*)(s + 4);
        *(short8v*)&Xs[row * 520 + lane * 8] = cvt8v(a0, a1);
    }
    __syncthreads();

    const int uv = w & 1, rh = w >> 1;
    const int rQ = lane >> 4, rM = lane & 15;
    float4v acc[2] = {};
#pragma unroll
    for (int ks = 0; ks < 16; ++ks) {
        int arow = rh * 16 + rM;
        short8v a = *(const short8v*)&Xs[arow * 520 + (ks * 4 + rQ) * 8];
#pragma unroll
        for (int nf = 0; nf < 2; ++nf) {
            int brow = uv * 32 + nf * 16 + rM;
            short8v bf = *(const short8v*)&Ws[brow * 520 + (ks * 4 + rQ) * 8];
            acc[nf] = __builtin_amdgcn_mfma_f32_16x16x32_bf16(a, bf, acc[nf], 0, 0, 0);
        }
    }
    __syncthreads();   // all LDS reads done; reuse for U/V fp32 [64][33]

    float* Us = (float*)smem;
    float* Vs = Us + 64 * 33;
    float* dst = uv ? Vs : Us;
#pragma unroll
    for (int nf = 0; nf < 2; ++nf)
#pragma unroll
        for (int r = 0; r < 4; ++r)
            dst[(rh * 16 + rQ * 4 + r) * 33 + nf * 16 + rM] = acc[nf][r];
    __syncthreads();

    // pairwise: p = tid&31, rows g*4..g*4+3 (g = tid>>5)
    const int p = tid & 31;
    const int g = tid >> 5;
    const float cv = cvec[p0 + p];
    float uf[4], red[4];
#pragma unroll
    for (int ii = 0; ii < 4; ++ii) {
        uf[ii] = Us[(g * 4 + ii) * 33 + p] + cv;
        red[ii] = 0.f;
    }
#pragma unroll 8
    for (int j = 0; j < 64; ++j) {
        float vs = Vs[j * 33 + p];
#pragma unroll
        for (int ii = 0; ii < 4; ++ii)
            red[ii] += fmaxf(uf[ii] + vs, 0.f);
    }
#pragma unroll
    for (int ii = 0; ii < 4; ++ii) {
        int i = g * 4 + ii;
        red[ii] -= fmaxf(uf[ii] + Vs[i * 33 + p], 0.f);
        out[(b * 64 + i) * 256 + p0 + p] = red[ii];
    }
}

// ---------------------------------------------------------------------------
extern "C" void kernel_launch(void* const* d_in, const int* in_sizes, int n_in,
                              void* d_out, int out_size, void* d_ws, size_t ws_size,
                              hipStream_t stream) {
    const float* x  = (const float*)d_in[0];   // (32,64,512)
    const float* W1 = (const float*)d_in[1];   // (256,1024)
    const float* b1 = (const float*)d_in[2];   // (256,)
    const float* W2 = (const float*)d_in[3];   // (256,256)
    const float* b2 = (const float*)d_in[4];   // (256,)
    float* out = (float*)d_out;                // (32,64,256)

    // workspace: Wfb (512*512 bf16 = 512KB) | cvec (256 f32)
    u16* Wfb = (u16*)d_ws;
    float* cvec = (float*)(Wfb + 512 * 512);

    prep_kernel<<<65, 256, 0, stream>>>(W1, b1, W2, b2, Wfb, cvec);
    fused_kernel<<<256, 512, 0, stream>>>(x, Wfb, cvec, out);
}